// Round 21
// baseline (203.540 us; speedup 1.0000x reference)
//
#include <hip/hip_runtime.h>
#include <hip/hip_bf16.h>
#include <hip/hip_fp16.h>

// Problem constants (match reference)
#define N_ATOMS 20000
#define N_EDGES 400000
#define NCH 4
#define F_IN 128
#define S_OUT 32

// ---------- helpers ----------
__device__ __forceinline__ float silu_f(float v) { return v / (1.f + __expf(-v)); }

typedef _Float16 half8v __attribute__((ext_vector_type(8)));
typedef float f32x4v __attribute__((ext_vector_type(4)));

__device__ __forceinline__ half8v ld_frag(const __half* p) {
    union { float4 f; half8v h; } u;
    u.f = *(const float4*)p;
    return u.h;
}

__device__ __forceinline__ int wave_iscan(int v, int l) {
#pragma unroll
    for (int off = 1; off < 64; off <<= 1) {
        int t = __shfl_up(v, off);
        if (l >= off) v += t;
    }
    return v;
}

// ---------- fill ----------
__global__ void fill_kernel(float* __restrict__ p, int n, float v) {
    int i = blockIdx.x * blockDim.x + threadIdx.x;
    int stride = gridDim.x * blockDim.x;
    for (; i < n; i += stride) p[i] = v;
}

// ---------- CSR build: histogram -> hierarchical scan -> scatter ----------
__global__ void hist_kernel(const int* __restrict__ ei, int* __restrict__ cnt, int E) {
    int e = blockIdx.x * 256 + threadIdx.x;
    if (e < E) atomicAdd(&cnt[ei[E + e]], 1);
}

__global__ __launch_bounds__(256) void scan_l1_kernel(const int* __restrict__ cnt,
                                                      int* __restrict__ rowp,
                                                      int* __restrict__ bsum, int n) {
    int i = blockIdx.x * 256 + threadIdx.x;
    int l = threadIdx.x & 63, w = threadIdx.x >> 6;
    int v = (i < n) ? cnt[i] : 0;
    int incl = wave_iscan(v, l);
    __shared__ int wsum[4];
    if (l == 63) wsum[w] = incl;
    __syncthreads();
    int add = 0;
#pragma unroll
    for (int j = 0; j < 4; ++j) add += (j < w) ? wsum[j] : 0;
    if (i < n) rowp[i] = add + incl - v;
    if (threadIdx.x == 255) bsum[blockIdx.x] = add + incl;
}

__global__ __launch_bounds__(256) void scan_l2_kernel(const int* __restrict__ bsum,
                                                      int* __restrict__ boff,
                                                      int* __restrict__ rowp_n, int nb,
                                                      float* __restrict__ out_zero) {
    int i = threadIdx.x;
    if (i < S_OUT) out_zero[i] = 0.f;  // fused energies zero-init
    int l = i & 63, w = i >> 6;
    int v = (i < nb) ? bsum[i] : 0;
    int incl = wave_iscan(v, l);
    __shared__ int wsum[4];
    if (l == 63) wsum[w] = incl;
    __syncthreads();
    int add = 0;
#pragma unroll
    for (int j = 0; j < 4; ++j) add += (j < w) ? wsum[j] : 0;
    if (i < nb) boff[i] = add + incl - v;
    if (i == nb - 1) *rowp_n = add + incl;
}

__global__ __launch_bounds__(256) void scan_l3_kernel(int* __restrict__ rowp,
                                                      const int* __restrict__ boff, int n) {
    int i = blockIdx.x * 256 + threadIdx.x;
    if (i < n) rowp[i] += boff[blockIdx.x];
}

__global__ void scatter_kernel(const int* __restrict__ ei, const int* __restrict__ rowp,
                               int* __restrict__ fill, int* __restrict__ csr_src, int E) {
    int e = blockIdx.x * 256 + threadIdx.x;
    if (e < E) {
        int d = ei[E + e];
        int pos = rowp[d] + atomicAdd(&fill[d], 1);
        csr_src[pos] = ei[e];
    }
}

// ---------- projection via MFMA: block = 64 nodes x 64 outputs, c = blockIdx.y ----------
// IN_CMAJ/OUT_CMAJ: channel-major planes [c][node][64] (gather-friendly layout).
template <int FIN, int IN_STRIDE, bool IN_HALF, bool IN_CMAJ, bool LN, bool ATT,
          bool SILU_OUT, bool OUT_HALF, bool OUT_CMAJ>
__global__ __launch_bounds__(256) void proj_kernel(const void* __restrict__ inv,
                                                   const float* __restrict__ gamma,
                                                   const float* __restrict__ beta,
                                                   const float* __restrict__ W,
                                                   const float* __restrict__ a_src,
                                                   const float* __restrict__ a_dst,
                                                   void* __restrict__ outv,
                                                   float* __restrict__ es,
                                                   float* __restrict__ ed) {
    constexpr int OCT = FIN / 8;      // octets per row
    constexpr int OM = OCT - 1;
    constexpr int WSH = FIN + 8;      // halves stride (rows 16B-aligned)
    __shared__ __half Wt[64 * WSH];   // [o][store-swizzled k]
    __shared__ __half inl[64 * WSH];  // [node][k] linear
    const int tid = threadIdx.x;
    const int c = blockIdx.y;
    const int n0 = blockIdx.x * 64;
    const int w = tid >> 6;           // wave 0..3
    const int l = tid & 63;
    const int col = l & 15;           // MFMA row/col lane index
    const int g = l >> 4;             // k-octet group 0..3

    const float* __restrict__ Wc = W + c * (FIN * 64);
    for (int i = tid; i < (FIN / 2) * 64; i += 256) {
        int kp = i >> 6, oo = i & 63;
        int k = kp * 2;
        float w0 = Wc[(size_t)k * 64 + oo];
        float w1 = Wc[(size_t)(k + 1) * 64 + oo];
        int pos = ((((k >> 3) ^ (oo >> 2)) & OM) << 3) | (k & 7);
        *(__half2*)(&Wt[oo * WSH + pos]) = __floats2half2_rn(w0, w1);
    }
    if (IN_HALF) {
        const __half* __restrict__ inh = (const __half*)inv;
        for (int i = tid; i < 64 * (FIN / 8); i += 256) {
            int nl = i / (FIN / 8), ch = i % (FIN / 8);
            int node = min(n0 + nl, N_ATOMS - 1);
            const __half* src = IN_CMAJ
                ? inh + ((size_t)c * N_ATOMS + node) * 64 + ch * 8
                : inh + (size_t)node * IN_STRIDE + c * FIN + ch * 8;
            *(float4*)(inl + nl * WSH + ch * 8) = *(const float4*)src;
        }
    } else {
        const float* __restrict__ inf = (const float*)inv;
        for (int i = tid; i < 64 * (FIN / 8); i += 256) {
            int nl = i / (FIN / 8), ch = i % (FIN / 8);
            int node = min(n0 + nl, N_ATOMS - 1);
            const float* src = inf + (size_t)node * IN_STRIDE + c * FIN + ch * 8;
            float4 a = *(const float4*)src;
            float4 b = *(const float4*)(src + 4);
            float4 st;
            __half2* sp = (__half2*)&st;
            sp[0] = __floats2half2_rn(a.x, a.y);
            sp[1] = __floats2half2_rn(a.z, a.w);
            sp[2] = __floats2half2_rn(b.x, b.y);
            sp[3] = __floats2half2_rn(b.z, b.w);
            *(float4*)(inl + nl * WSH + ch * 8) = st;
        }
    }
    __syncthreads();

    if (LN) {  // parallel LayerNorm: 4 rows/wave concurrently, 16-lane-group reduce
        int sub = l >> 4;      // row subgroup 0..3
        int l16 = l & 15;
        float gv[8], bv8[8];
#pragma unroll
        for (int j = 0; j < 8; ++j) {
            gv[j] = gamma[l16 * 8 + j];
            bv8[j] = beta[l16 * 8 + j];
        }
#pragma unroll
        for (int it = 0; it < 4; ++it) {
            int row = w * 16 + it * 4 + sub;
            __half* rp = inl + row * WSH + l16 * 8;
            float4 raw = *(const float4*)rp;
            __half2* hp = (__half2*)&raw;
            float v[8];
#pragma unroll
            for (int j = 0; j < 4; ++j) {
                float2 f = __half22float2(hp[j]);
                v[2 * j] = f.x;
                v[2 * j + 1] = f.y;
            }
            float s = 0.f, sq = 0.f;
#pragma unroll
            for (int j = 0; j < 8; ++j) { s += v[j]; sq += v[j] * v[j]; }
#pragma unroll
            for (int off = 1; off < 16; off <<= 1) {
                s += __shfl_xor(s, off);
                sq += __shfl_xor(sq, off);
            }
            float mu = s * (1.f / 128.f);
            float rs = rsqrtf(sq * (1.f / 128.f) - mu * mu + 1e-5f);
            float4 st;
            __half2* sp = (__half2*)&st;
#pragma unroll
            for (int j = 0; j < 4; ++j)
                sp[j] = __floats2half2_rn((v[2 * j] - mu) * rs * gv[2 * j] + bv8[2 * j],
                                          (v[2 * j + 1] - mu) * rs * gv[2 * j + 1] + bv8[2 * j + 1]);
            *(float4*)rp = st;
        }
        __syncthreads();
    }

    f32x4v acc[4];
#pragma unroll
    for (int t = 0; t < 4; ++t) acc[t] = (f32x4v){0.f, 0.f, 0.f, 0.f};

    const __half* arow = inl + (w * 16 + col) * WSH + g * 8;
#pragma unroll
    for (int it = 0; it < FIN / 32; ++it) {
        half8v af = ld_frag(arow + it * 32);
        int J = it * 4 + g;
#pragma unroll
        for (int t = 0; t < 4; ++t) {
            int oo = 16 * t + col;
            half8v bf = ld_frag(Wt + oo * WSH + (((J ^ (oo >> 2)) & OM) << 3));
            acc[t] = __builtin_amdgcn_mfma_f32_16x16x32_f16(af, bf, acc[t], 0, 0, 0);
        }
    }

    // epilogue: D layout col=lane&15, row=(lane>>4)*4+reg
    float av[4], bv[4];
    if (ATT) {
#pragma unroll
        for (int t = 0; t < 4; ++t) {
            av[t] = a_src[c * 64 + 16 * t + col];
            bv[t] = a_dst[c * 64 + 16 * t + col];
        }
    }
#pragma unroll
    for (int r = 0; r < 4; ++r) {
        int node = n0 + w * 16 + g * 4 + r;
        bool valid = node < N_ATOMS;
        if (valid) {
#pragma unroll
            for (int t = 0; t < 4; ++t) {
                float o = acc[t][r];
                if (SILU_OUT) o = silu_f(o);
                size_t idx = OUT_CMAJ ? ((size_t)c * N_ATOMS + node) * 64 + 16 * t + col
                                      : (size_t)node * 256 + c * 64 + 16 * t + col;
                if (OUT_HALF)
                    ((__half*)outv)[idx] = __float2half(o);
                else
                    ((float*)outv)[idx] = o;
            }
        }
        if (ATT) {
            float ps = 0.f, pd = 0.f;
#pragma unroll
            for (int t = 0; t < 4; ++t) {
                ps = fmaf(acc[t][r], av[t], ps);
                pd = fmaf(acc[t][r], bv[t], pd);
            }
#pragma unroll
            for (int off = 1; off < 16; off <<= 1) {
                ps += __shfl_xor(ps, off);
                pd += __shfl_xor(pd, off);
            }
            if (col == 0 && valid) { es[node * NCH + c] = ps; ed[node * NCH + c] = pd; }
        }
    }
}

// ---------- GAT aggregation: channel-phased for L2 residency ----------
// grid (N/4, NCH); wave = (dst, c=blockIdx.y). h is channel-major [c][node][64]
// (one 2.56MB plane per phase -> fits 4MB per-XCD L2). 4 groups of 16 lanes
// process 4 edges concurrently (512B/load); softmax phase A group-redundant.
__global__ __launch_bounds__(256) void gat_gather_kernel(const int* __restrict__ rowp,
                                                         const int* __restrict__ csr_src,
                                                         const float* __restrict__ es,
                                                         const float* __restrict__ ed,
                                                         const __half* __restrict__ h,
                                                         __half* __restrict__ out) {
    int l = threadIdx.x & 63;
    int d = blockIdx.x * 4 + (threadIdx.x >> 6);
    int c = blockIdx.y;
    int q = l & 15;   // edge slot (phase A) / feature quad (phase B)
    int g = l >> 4;   // group
    int grp = l & 48;
    const __half* __restrict__ hc = h + (size_t)c * N_ATOMS * 64;
    int r0 = rowp[d], r1 = rowp[d + 1];
    float edc = ed[d * NCH + c];
    float m = -1e30f, den = 0.f;
    float a0 = 0.f, a1 = 0.f, a2 = 0.f, a3 = 0.f;

    for (int base = r0; base < r1; base += 16) {
        int len = min(16, r1 - base);
        // phase A (all groups redundant): 16 logits, 16-lane reduce
        float logit = -1e30f;
        int s = 0;
        if (q < len) {
            s = csr_src[base + q];
            float v = es[s * NCH + c] + edc;
            logit = v >= 0.f ? v : 0.2f * v;
        }
        float cm = logit;
#pragma unroll
        for (int off = 8; off; off >>= 1) cm = fmaxf(cm, __shfl_xor(cm, off));
        float nm = fmaxf(m, cm);
        float resc = __expf(m - nm);
        float ex = (q < len) ? __expf(logit - nm) : 0.f;
        float cs = ex;
#pragma unroll
        for (int off = 8; off; off >>= 1) cs += __shfl_xor(cs, off);
        den = den * resc + cs;
        a0 *= resc; a1 *= resc; a2 *= resc; a3 *= resc;
        m = nm;
        // phase B: group g handles edges e = g+4j; one 512B load serves 4 edges
#pragma unroll
        for (int j = 0; j < 4; ++j) {
            int e = g + 4 * j;
            bool act = e < len;
            int ee = act ? e : 0;
            float xe = __shfl(ex, grp | ee);   // bpermute (per-group broadcast)
            int se = __shfl(s, grp | ee);
            xe = act ? xe : 0.f;
            float2 hv = *(const float2*)(hc + (size_t)se * 64 + q * 4);
            __half2* hp = (__half2*)&hv;
            float2 f0 = __half22float2(hp[0]), f1 = __half22float2(hp[1]);
            a0 = fmaf(xe, f0.x, a0);
            a1 = fmaf(xe, f0.y, a1);
            a2 = fmaf(xe, f1.x, a2);
            a3 = fmaf(xe, f1.y, a3);
        }
    }
    // combine group partials (m, den consistent across groups)
#pragma unroll
    for (int off = 16; off < 64; off <<= 1) {
        a0 += __shfl_xor(a0, off);
        a1 += __shfl_xor(a1, off);
        a2 += __shfl_xor(a2, off);
        a3 += __shfl_xor(a3, off);
    }
    if (g == 0) {
        float inv = 1.f / (den + 1e-16f);
        float2 st;
        __half2* sp = (__half2*)&st;
        sp[0] = __floats2half2_rn(silu_f(a0 * inv), silu_f(a1 * inv));
        sp[1] = __floats2half2_rn(silu_f(a2 * inv), silu_f(a3 * inv));
        *(float2*)(out + ((size_t)c * N_ATOMS + d) * 64 + q * 4) = st;
    }
}

// ---------- fused MLP head: two MFMA stages (64->64->32->1) + energy reduction ----------
// input channel-major [c][node][64]
__global__ __launch_bounds__(256) void mlp_fused_kernel(const __half* __restrict__ in,
                                                        const float* __restrict__ W1,
                                                        const float* __restrict__ W2,
                                                        const float* __restrict__ W3,
                                                        const int* __restrict__ bat,
                                                        float* __restrict__ out) {
    constexpr int WSH = 72;           // 64+8 halves
    __shared__ __half W1t[64 * WSH];  // [o][swz k] for current channel
    __shared__ __half inl[64 * WSH];  // [node][k]
    __shared__ __half t1l[64 * WSH];  // [node][o] (linear)
    __shared__ __half W2t[NCH][32 * WSH];  // all channels, staged once
    __shared__ float w3l[NCH * 32];
    __shared__ float ynode[64];
    const int tid = threadIdx.x;
    const int n0 = blockIdx.x * 64;
    const int w = tid >> 6;
    const int l = tid & 63;
    const int col = l & 15;
    const int g = l >> 4;

    for (int i = tid; i < NCH * 32 * 32; i += 256) {
        int cc = i >> 10, rem = i & 1023;
        int kp = rem >> 5, o2 = rem & 31;
        int k = kp * 2;
        float a = W2[cc * 2048 + k * 32 + o2];
        float b = W2[cc * 2048 + (k + 1) * 32 + o2];
        int pos = ((((k >> 3) ^ (o2 >> 2)) & 7) << 3) | (k & 7);
        *(__half2*)(&W2t[cc][o2 * WSH + pos]) = __floats2half2_rn(a, b);
    }
    if (tid < NCH * 32) w3l[tid] = W3[tid];

    float yacc[4] = {0.f, 0.f, 0.f, 0.f};

    for (int c = 0; c < NCH; ++c) {
        __syncthreads();
        for (int i = tid; i < 32 * 64; i += 256) {
            int kp = i >> 6, oo = i & 63;
            int k = kp * 2;
            float a = W1[c * 4096 + k * 64 + oo];
            float b = W1[c * 4096 + (k + 1) * 64 + oo];
            int pos = ((((k >> 3) ^ (oo >> 2)) & 7) << 3) | (k & 7);
            *(__half2*)(&W1t[oo * WSH + pos]) = __floats2half2_rn(a, b);
        }
        for (int i = tid; i < 64 * 8; i += 256) {
            int nl = i >> 3, ch = i & 7;
            int node = min(n0 + nl, N_ATOMS - 1);
            *(float4*)(inl + nl * WSH + ch * 8) =
                *(const float4*)(in + ((size_t)c * N_ATOMS + node) * 64 + ch * 8);
        }
        __syncthreads();

        f32x4v acc[4];
#pragma unroll
        for (int t = 0; t < 4; ++t) acc[t] = (f32x4v){0.f, 0.f, 0.f, 0.f};
        const __half* arow = inl + (w * 16 + col) * WSH + g * 8;
#pragma unroll
        for (int it = 0; it < 2; ++it) {
            half8v af = ld_frag(arow + it * 32);
            int J = it * 4 + g;
#pragma unroll
            for (int t = 0; t < 4; ++t) {
                int oo = 16 * t + col;
                half8v bf = ld_frag(W1t + oo * WSH + (((J ^ (oo >> 2)) & 7) << 3));
                acc[t] = __builtin_amdgcn_mfma_f32_16x16x32_f16(af, bf, acc[t], 0, 0, 0);
            }
        }
#pragma unroll
        for (int t = 0; t < 4; ++t)
#pragma unroll
            for (int r = 0; r < 4; ++r)
                t1l[(w * 16 + g * 4 + r) * WSH + 16 * t + col] = __float2half(silu_f(acc[t][r]));

        f32x4v acc2[2];
        acc2[0] = (f32x4v){0.f, 0.f, 0.f, 0.f};
        acc2[1] = (f32x4v){0.f, 0.f, 0.f, 0.f};
        const __half* arow2 = t1l + (w * 16 + col) * WSH + g * 8;
#pragma unroll
        for (int it = 0; it < 2; ++it) {
            half8v af = ld_frag(arow2 + it * 32);
            int J = it * 4 + g;
#pragma unroll
            for (int t = 0; t < 2; ++t) {
                int o2 = 16 * t + col;
                half8v bf = ld_frag(&W2t[c][o2 * WSH + (((J ^ (o2 >> 2)) & 7) << 3)]);
                acc2[t] = __builtin_amdgcn_mfma_f32_16x16x32_f16(af, bf, acc2[t], 0, 0, 0);
            }
        }
        float w3a = w3l[c * 32 + col], w3b = w3l[c * 32 + 16 + col];
#pragma unroll
        for (int r = 0; r < 4; ++r) {
            float p = silu_f(acc2[0][r]) * w3a + silu_f(acc2[1][r]) * w3b;
#pragma unroll
            for (int off = 1; off < 16; off <<= 1) p += __shfl_xor(p, off);
            yacc[r] += p;
        }
    }

    if (col == 0) {
#pragma unroll
        for (int r = 0; r < 4; ++r) ynode[w * 16 + g * 4 + r] = yacc[r];
    }
    __syncthreads();
    if (tid < 64) {
        int node = n0 + tid;
        bool act = node < N_ATOMS;
        float val = act ? ynode[tid] * 0.025f : 0.f;  // /sqrt(4)/20
        int b = act ? bat[min(node, N_ATOMS - 1)] : 0;
        unsigned long long rem = __ballot(act);
        while (rem) {
            int lead = (int)__ffsll(rem) - 1;
            int bl = __shfl(b, lead);
            bool mine = act && (b == bl);
            float t = mine ? val : 0.f;
#pragma unroll
            for (int off = 32; off; off >>= 1) t += __shfl_xor(t, off);
            if (tid == lead) atomicAdd(out + bl, t);
            rem &= ~__ballot(mine);
        }
    }
}

extern "C" void kernel_launch(void* const* d_in, const int* in_sizes, int n_in,
                              void* d_out, int out_size, void* d_ws, size_t ws_size,
                              hipStream_t stream) {
    const float* x     = (const float*)d_in[0];
    const int*   ei    = (const int*)d_in[1];
    const int*   bat   = (const int*)d_in[2];
    const float* gamma = (const float*)d_in[3];
    const float* beta  = (const float*)d_in[4];
    const float* Wc1   = (const float*)d_in[5];
    const float* as1   = (const float*)d_in[6];
    const float* ad1   = (const float*)d_in[7];
    const float* Wc2   = (const float*)d_in[8];
    const float* as2   = (const float*)d_in[9];
    const float* ad2   = (const float*)d_in[10];
    const float* Wn1   = (const float*)d_in[11];
    const float* Wn2   = (const float*)d_in[12];
    const float* Wout  = (const float*)d_in[13];
    float* out = (float*)d_out;

    // workspace layout (floats)
    float* A    = (float*)d_ws;            // C1h/C2h fp16 conv outs (channel-major)
    float* B    = A + 10240000;            // Bh fp16 proj h (channel-major)
    float* es   = B + 5120000;             // 80k
    float* ed   = es + 80000;              // 80k
    int* rowp   = (int*)(ed + 80000);      // 20001 (pad 20004)
    int* cnt    = rowp + 20004;            // 20000
    int* fillc  = cnt + 20000;             // 20000
    int* csr    = fillc + 20000;           // 400000
    int* bsum   = csr + 400000;            // 128
    int* boff   = bsum + 128;              // 128
    __half* C1h = (__half*)A;              // conv1 out (silu'd, fp16) [C][N][64]
    __half* C2h = (__half*)(A + 2560000);  // conv2 out (silu'd, fp16) [C][N][64]
    __half* Bh  = (__half*)B;              // proj h (fp16) [C][N][64]

    dim3 blk(256);
    const int NB = (N_ATOMS + 255) / 256;   // 79
    const int NT64 = (N_ATOMS + 63) / 64;   // 313

    // ---- CSR build (graph is shared by both convs) ----
    fill_kernel<<<80, blk, 0, stream>>>((float*)cnt, 40000, 0.f);  // cnt + fillc (adjacent)
    hist_kernel<<<(N_EDGES + 255) / 256, blk, 0, stream>>>(ei, cnt, N_EDGES);
    scan_l1_kernel<<<NB, blk, 0, stream>>>(cnt, rowp, bsum, N_ATOMS);
    scan_l2_kernel<<<1, blk, 0, stream>>>(bsum, boff, rowp + N_ATOMS, NB, out);
    scan_l3_kernel<<<NB, blk, 0, stream>>>(rowp, boff, N_ATOMS);
    scatter_kernel<<<(N_EDGES + 255) / 256, blk, 0, stream>>>(ei, rowp, fillc, csr, N_EDGES);

    // ---- conv1 (LN fused; h fp16 channel-major) ----
    proj_kernel<128, NCH * F_IN, false, false, true, true, false, true, true>
        <<<dim3(NT64, NCH), blk, 0, stream>>>(x, gamma, beta, Wc1, as1, ad1, Bh, es, ed);
    gat_gather_kernel<<<dim3(N_ATOMS / 4, NCH), blk, 0, stream>>>(rowp, csr, es, ed, Bh, C1h);

    // ---- conv2 (channel-major fp16 in/out) ----
    proj_kernel<64, 64, true, true, false, true, false, true, true>
        <<<dim3(NT64, NCH), blk, 0, stream>>>(C1h, gamma, beta, Wc2, as2, ad2, Bh, es, ed);
    gat_gather_kernel<<<dim3(N_ATOMS / 4, NCH), blk, 0, stream>>>(rowp, csr, es, ed, Bh, C2h);

    // ---- fused MLP head: two MFMA stages + energy reduction ----
    mlp_fused_kernel<<<NT64, blk, 0, stream>>>(C2h, Wn1, Wn2, Wout, bat, out);
}

// Round 22
// 173.597 us; speedup vs baseline: 1.1725x; 1.1725x over previous
//
#include <hip/hip_runtime.h>
#include <hip/hip_bf16.h>
#include <hip/hip_fp16.h>

// Problem constants (match reference)
#define N_ATOMS 20000
#define N_EDGES 400000
#define NCH 4
#define F_IN 128
#define S_OUT 32

// ---------- helpers ----------
__device__ __forceinline__ float silu_f(float v) { return v / (1.f + __expf(-v)); }

typedef _Float16 half8v __attribute__((ext_vector_type(8)));
typedef float f32x4v __attribute__((ext_vector_type(4)));

__device__ __forceinline__ half8v ld_frag(const __half* p) {
    union { float4 f; half8v h; } u;
    u.f = *(const float4*)p;
    return u.h;
}

__device__ __forceinline__ int wave_iscan(int v, int l) {
#pragma unroll
    for (int off = 1; off < 64; off <<= 1) {
        int t = __shfl_up(v, off);
        if (l >= off) v += t;
    }
    return v;
}

// ---------- fill ----------
__global__ void fill_kernel(float* __restrict__ p, int n, float v) {
    int i = blockIdx.x * blockDim.x + threadIdx.x;
    int stride = gridDim.x * blockDim.x;
    for (; i < n; i += stride) p[i] = v;
}

// ---------- CSR build: histogram -> hierarchical scan -> scatter ----------
__global__ void hist_kernel(const int* __restrict__ ei, int* __restrict__ cnt, int E) {
    int e = blockIdx.x * 256 + threadIdx.x;
    if (e < E) atomicAdd(&cnt[ei[E + e]], 1);
}

__global__ __launch_bounds__(256) void scan_l1_kernel(const int* __restrict__ cnt,
                                                      int* __restrict__ rowp,
                                                      int* __restrict__ bsum, int n) {
    int i = blockIdx.x * 256 + threadIdx.x;
    int l = threadIdx.x & 63, w = threadIdx.x >> 6;
    int v = (i < n) ? cnt[i] : 0;
    int incl = wave_iscan(v, l);
    __shared__ int wsum[4];
    if (l == 63) wsum[w] = incl;
    __syncthreads();
    int add = 0;
#pragma unroll
    for (int j = 0; j < 4; ++j) add += (j < w) ? wsum[j] : 0;
    if (i < n) rowp[i] = add + incl - v;
    if (threadIdx.x == 255) bsum[blockIdx.x] = add + incl;
}

__global__ __launch_bounds__(256) void scan_l2_kernel(const int* __restrict__ bsum,
                                                      int* __restrict__ boff,
                                                      int* __restrict__ rowp_n, int nb,
                                                      float* __restrict__ out_zero) {
    int i = threadIdx.x;
    if (i < S_OUT) out_zero[i] = 0.f;  // fused energies zero-init
    int l = i & 63, w = i >> 6;
    int v = (i < nb) ? bsum[i] : 0;
    int incl = wave_iscan(v, l);
    __shared__ int wsum[4];
    if (l == 63) wsum[w] = incl;
    __syncthreads();
    int add = 0;
#pragma unroll
    for (int j = 0; j < 4; ++j) add += (j < w) ? wsum[j] : 0;
    if (i < nb) boff[i] = add + incl - v;
    if (i == nb - 1) *rowp_n = add + incl;
}

__global__ __launch_bounds__(256) void scan_l3_kernel(int* __restrict__ rowp,
                                                      const int* __restrict__ boff, int n) {
    int i = blockIdx.x * 256 + threadIdx.x;
    if (i < n) rowp[i] += boff[blockIdx.x];
}

__global__ void scatter_kernel(const int* __restrict__ ei, const int* __restrict__ rowp,
                               int* __restrict__ fill, int* __restrict__ csr_src, int E) {
    int e = blockIdx.x * 256 + threadIdx.x;
    if (e < E) {
        int d = ei[E + e];
        int pos = rowp[d] + atomicAdd(&fill[d], 1);
        csr_src[pos] = ei[e];
    }
}

// ---------- projection via MFMA: block = 64 nodes x 64 outputs, c = blockIdx.y ----------
// IN_CMAJ/OUT_CMAJ: channel-major planes [c][node][64]. es/ed channel-major [c][node].
template <int FIN, int IN_STRIDE, bool IN_HALF, bool IN_CMAJ, bool LN, bool ATT,
          bool SILU_OUT, bool OUT_HALF, bool OUT_CMAJ>
__global__ __launch_bounds__(256) void proj_kernel(const void* __restrict__ inv,
                                                   const float* __restrict__ gamma,
                                                   const float* __restrict__ beta,
                                                   const float* __restrict__ W,
                                                   const float* __restrict__ a_src,
                                                   const float* __restrict__ a_dst,
                                                   void* __restrict__ outv,
                                                   float* __restrict__ es,
                                                   float* __restrict__ ed) {
    constexpr int OCT = FIN / 8;      // octets per row
    constexpr int OM = OCT - 1;
    constexpr int WSH = FIN + 8;      // halves stride (rows 16B-aligned)
    __shared__ __half Wt[64 * WSH];   // [o][store-swizzled k]
    __shared__ __half inl[64 * WSH];  // [node][k] linear
    const int tid = threadIdx.x;
    const int c = blockIdx.y;
    const int n0 = blockIdx.x * 64;
    const int w = tid >> 6;           // wave 0..3
    const int l = tid & 63;
    const int col = l & 15;           // MFMA row/col lane index
    const int g = l >> 4;             // k-octet group 0..3

    const float* __restrict__ Wc = W + c * (FIN * 64);
    for (int i = tid; i < (FIN / 2) * 64; i += 256) {
        int kp = i >> 6, oo = i & 63;
        int k = kp * 2;
        float w0 = Wc[(size_t)k * 64 + oo];
        float w1 = Wc[(size_t)(k + 1) * 64 + oo];
        int pos = ((((k >> 3) ^ (oo >> 2)) & OM) << 3) | (k & 7);
        *(__half2*)(&Wt[oo * WSH + pos]) = __floats2half2_rn(w0, w1);
    }
    if (IN_HALF) {
        const __half* __restrict__ inh = (const __half*)inv;
        for (int i = tid; i < 64 * (FIN / 8); i += 256) {
            int nl = i / (FIN / 8), ch = i % (FIN / 8);
            int node = min(n0 + nl, N_ATOMS - 1);
            const __half* src = IN_CMAJ
                ? inh + ((size_t)c * N_ATOMS + node) * 64 + ch * 8
                : inh + (size_t)node * IN_STRIDE + c * FIN + ch * 8;
            *(float4*)(inl + nl * WSH + ch * 8) = *(const float4*)src;
        }
    } else {
        const float* __restrict__ inf = (const float*)inv;
        for (int i = tid; i < 64 * (FIN / 8); i += 256) {
            int nl = i / (FIN / 8), ch = i % (FIN / 8);
            int node = min(n0 + nl, N_ATOMS - 1);
            const float* src = inf + (size_t)node * IN_STRIDE + c * FIN + ch * 8;
            float4 a = *(const float4*)src;
            float4 b = *(const float4*)(src + 4);
            float4 st;
            __half2* sp = (__half2*)&st;
            sp[0] = __floats2half2_rn(a.x, a.y);
            sp[1] = __floats2half2_rn(a.z, a.w);
            sp[2] = __floats2half2_rn(b.x, b.y);
            sp[3] = __floats2half2_rn(b.z, b.w);
            *(float4*)(inl + nl * WSH + ch * 8) = st;
        }
    }
    __syncthreads();

    if (LN) {  // parallel LayerNorm: 4 rows/wave concurrently, 16-lane-group reduce
        int sub = l >> 4;
        int l16 = l & 15;
        float gv[8], bv8[8];
#pragma unroll
        for (int j = 0; j < 8; ++j) {
            gv[j] = gamma[l16 * 8 + j];
            bv8[j] = beta[l16 * 8 + j];
        }
#pragma unroll
        for (int it = 0; it < 4; ++it) {
            int row = w * 16 + it * 4 + sub;
            __half* rp = inl + row * WSH + l16 * 8;
            float4 raw = *(const float4*)rp;
            __half2* hp = (__half2*)&raw;
            float v[8];
#pragma unroll
            for (int j = 0; j < 4; ++j) {
                float2 f = __half22float2(hp[j]);
                v[2 * j] = f.x;
                v[2 * j + 1] = f.y;
            }
            float s = 0.f, sq = 0.f;
#pragma unroll
            for (int j = 0; j < 8; ++j) { s += v[j]; sq += v[j] * v[j]; }
#pragma unroll
            for (int off = 1; off < 16; off <<= 1) {
                s += __shfl_xor(s, off);
                sq += __shfl_xor(sq, off);
            }
            float mu = s * (1.f / 128.f);
            float rs = rsqrtf(sq * (1.f / 128.f) - mu * mu + 1e-5f);
            float4 st;
            __half2* sp = (__half2*)&st;
#pragma unroll
            for (int j = 0; j < 4; ++j)
                sp[j] = __floats2half2_rn((v[2 * j] - mu) * rs * gv[2 * j] + bv8[2 * j],
                                          (v[2 * j + 1] - mu) * rs * gv[2 * j + 1] + bv8[2 * j + 1]);
            *(float4*)rp = st;
        }
        __syncthreads();
    }

    f32x4v acc[4];
#pragma unroll
    for (int t = 0; t < 4; ++t) acc[t] = (f32x4v){0.f, 0.f, 0.f, 0.f};

    const __half* arow = inl + (w * 16 + col) * WSH + g * 8;
#pragma unroll
    for (int it = 0; it < FIN / 32; ++it) {
        half8v af = ld_frag(arow + it * 32);
        int J = it * 4 + g;
#pragma unroll
        for (int t = 0; t < 4; ++t) {
            int oo = 16 * t + col;
            half8v bf = ld_frag(Wt + oo * WSH + (((J ^ (oo >> 2)) & OM) << 3));
            acc[t] = __builtin_amdgcn_mfma_f32_16x16x32_f16(af, bf, acc[t], 0, 0, 0);
        }
    }

    // epilogue: D layout col=lane&15, row=(lane>>4)*4+reg
    float av[4], bv[4];
    if (ATT) {
#pragma unroll
        for (int t = 0; t < 4; ++t) {
            av[t] = a_src[c * 64 + 16 * t + col];
            bv[t] = a_dst[c * 64 + 16 * t + col];
        }
    }
#pragma unroll
    for (int r = 0; r < 4; ++r) {
        int node = n0 + w * 16 + g * 4 + r;
        bool valid = node < N_ATOMS;
        if (valid) {
#pragma unroll
            for (int t = 0; t < 4; ++t) {
                float o = acc[t][r];
                if (SILU_OUT) o = silu_f(o);
                size_t idx = OUT_CMAJ ? ((size_t)c * N_ATOMS + node) * 64 + 16 * t + col
                                      : (size_t)node * 256 + c * 64 + 16 * t + col;
                if (OUT_HALF)
                    ((__half*)outv)[idx] = __float2half(o);
                else
                    ((float*)outv)[idx] = o;
            }
        }
        if (ATT) {
            float ps = 0.f, pd = 0.f;
#pragma unroll
            for (int t = 0; t < 4; ++t) {
                ps = fmaf(acc[t][r], av[t], ps);
                pd = fmaf(acc[t][r], bv[t], pd);
            }
#pragma unroll
            for (int off = 1; off < 16; off <<= 1) {
                ps += __shfl_xor(ps, off);
                pd += __shfl_xor(pd, off);
            }
            if (col == 0 && valid) {
                es[(size_t)c * N_ATOMS + node] = ps;   // channel-major
                ed[(size_t)c * N_ATOMS + node] = pd;
            }
        }
    }
}

// ---------- GAT aggregation: channel-phased, wave = 4 dsts x 1 channel ----------
// grid (N/16, NCH); lane group g owns dst base+w*4+g. Phase A: 4 dsts' softmax in
// parallel (16-lane reduces). Phase B: group streams its dst's 128B rows; ex==0
// beyond len so loads are unconditional (tail re-reads L1-hot row 0).
__global__ __launch_bounds__(256) void gat_gather_kernel(const int* __restrict__ rowp,
                                                         const int* __restrict__ csr_src,
                                                         const float* __restrict__ es,
                                                         const float* __restrict__ ed,
                                                         const __half* __restrict__ h,
                                                         __half* __restrict__ out) {
    int l = threadIdx.x & 63;
    int wv = threadIdx.x >> 6;
    int c = blockIdx.y;
    int g = l >> 4, q = l & 15, grp = l & 48;
    int d = blockIdx.x * 16 + wv * 4 + g;          // N divisible by 16
    const __half* __restrict__ hc = h + (size_t)c * N_ATOMS * 64;
    const float* __restrict__ esc = es + (size_t)c * N_ATOMS;
    int r0 = rowp[d], r1 = rowp[d + 1];
    int deg = r1 - r0;
    float edc = ed[(size_t)c * N_ATOMS + d];
    int maxdeg = deg;
#pragma unroll
    for (int off = 16; off < 64; off <<= 1) maxdeg = max(maxdeg, __shfl_xor(maxdeg, off));

    float m = -1e30f, den = 0.f;
    float a0 = 0.f, a1 = 0.f, a2 = 0.f, a3 = 0.f;

    for (int bo = 0; bo < maxdeg; bo += 16) {
        int len = min(16, deg - bo);               // may be <= 0 for finished groups
        // phase A: lanes q = edge slots within the group
        float logit = -1e30f;
        int s = 0;
        if (q < len) {
            s = csr_src[r0 + bo + q];
            float v = esc[s] + edc;
            logit = v >= 0.f ? v : 0.2f * v;
        }
        float cm = logit;
#pragma unroll
        for (int off = 8; off; off >>= 1) cm = fmaxf(cm, __shfl_xor(cm, off));
        float nm = fmaxf(m, cm);
        float resc = __expf(m - nm);
        float ex = (q < len) ? __expf(logit - nm) : 0.f;
        float cs = ex;
#pragma unroll
        for (int off = 8; off; off >>= 1) cs += __shfl_xor(cs, off);
        den = den * resc + cs;
        a0 *= resc; a1 *= resc; a2 *= resc; a3 *= resc;
        m = nm;
        // phase B: 4-wide unrolled; ex beyond len is 0 (loads may hit row 0)
#pragma unroll
        for (int e = 0; e < 16; e += 4) {
            int s0 = __shfl(s, grp | e),       s1 = __shfl(s, grp | (e + 1));
            int s2 = __shfl(s, grp | (e + 2)), s3 = __shfl(s, grp | (e + 3));
            float x0 = __shfl(ex, grp | e),       x1 = __shfl(ex, grp | (e + 1));
            float x2 = __shfl(ex, grp | (e + 2)), x3 = __shfl(ex, grp | (e + 3));
            float2 hv0 = *(const float2*)(hc + (size_t)s0 * 64 + q * 4);
            float2 hv1 = *(const float2*)(hc + (size_t)s1 * 64 + q * 4);
            float2 hv2 = *(const float2*)(hc + (size_t)s2 * 64 + q * 4);
            float2 hv3 = *(const float2*)(hc + (size_t)s3 * 64 + q * 4);
            __half2* p0 = (__half2*)&hv0;
            __half2* p1 = (__half2*)&hv1;
            __half2* p2 = (__half2*)&hv2;
            __half2* p3 = (__half2*)&hv3;
            float2 f00 = __half22float2(p0[0]), f01 = __half22float2(p0[1]);
            float2 f10 = __half22float2(p1[0]), f11 = __half22float2(p1[1]);
            float2 f20 = __half22float2(p2[0]), f21 = __half22float2(p2[1]);
            float2 f30 = __half22float2(p3[0]), f31 = __half22float2(p3[1]);
            a0 = fmaf(x0, f00.x, fmaf(x1, f10.x, fmaf(x2, f20.x, fmaf(x3, f30.x, a0))));
            a1 = fmaf(x0, f00.y, fmaf(x1, f10.y, fmaf(x2, f20.y, fmaf(x3, f30.y, a1))));
            a2 = fmaf(x0, f01.x, fmaf(x1, f11.x, fmaf(x2, f21.x, fmaf(x3, f31.x, a2))));
            a3 = fmaf(x0, f01.y, fmaf(x1, f11.y, fmaf(x2, f21.y, fmaf(x3, f31.y, a3))));
        }
    }
    float inv = 1.f / (den + 1e-16f);
    float2 st;
    __half2* sp = (__half2*)&st;
    sp[0] = __floats2half2_rn(silu_f(a0 * inv), silu_f(a1 * inv));
    sp[1] = __floats2half2_rn(silu_f(a2 * inv), silu_f(a3 * inv));
    *(float2*)(out + ((size_t)c * N_ATOMS + d) * 64 + q * 4) = st;
}

// ---------- fused MLP head: two MFMA stages (64->64->32->1) + energy reduction ----------
// input channel-major [c][node][64]
__global__ __launch_bounds__(256) void mlp_fused_kernel(const __half* __restrict__ in,
                                                        const float* __restrict__ W1,
                                                        const float* __restrict__ W2,
                                                        const float* __restrict__ W3,
                                                        const int* __restrict__ bat,
                                                        float* __restrict__ out) {
    constexpr int WSH = 72;           // 64+8 halves
    __shared__ __half W1t[64 * WSH];  // [o][swz k] for current channel
    __shared__ __half inl[64 * WSH];  // [node][k]
    __shared__ __half t1l[64 * WSH];  // [node][o] (linear)
    __shared__ __half W2t[NCH][32 * WSH];  // all channels, staged once
    __shared__ float w3l[NCH * 32];
    __shared__ float ynode[64];
    const int tid = threadIdx.x;
    const int n0 = blockIdx.x * 64;
    const int w = tid >> 6;
    const int l = tid & 63;
    const int col = l & 15;
    const int g = l >> 4;

    for (int i = tid; i < NCH * 32 * 32; i += 256) {
        int cc = i >> 10, rem = i & 1023;
        int kp = rem >> 5, o2 = rem & 31;
        int k = kp * 2;
        float a = W2[cc * 2048 + k * 32 + o2];
        float b = W2[cc * 2048 + (k + 1) * 32 + o2];
        int pos = ((((k >> 3) ^ (o2 >> 2)) & 7) << 3) | (k & 7);
        *(__half2*)(&W2t[cc][o2 * WSH + pos]) = __floats2half2_rn(a, b);
    }
    if (tid < NCH * 32) w3l[tid] = W3[tid];

    float yacc[4] = {0.f, 0.f, 0.f, 0.f};

    for (int c = 0; c < NCH; ++c) {
        __syncthreads();
        for (int i = tid; i < 32 * 64; i += 256) {
            int kp = i >> 6, oo = i & 63;
            int k = kp * 2;
            float a = W1[c * 4096 + k * 64 + oo];
            float b = W1[c * 4096 + (k + 1) * 64 + oo];
            int pos = ((((k >> 3) ^ (oo >> 2)) & 7) << 3) | (k & 7);
            *(__half2*)(&W1t[oo * WSH + pos]) = __floats2half2_rn(a, b);
        }
        for (int i = tid; i < 64 * 8; i += 256) {
            int nl = i >> 3, ch = i & 7;
            int node = min(n0 + nl, N_ATOMS - 1);
            *(float4*)(inl + nl * WSH + ch * 8) =
                *(const float4*)(in + ((size_t)c * N_ATOMS + node) * 64 + ch * 8);
        }
        __syncthreads();

        f32x4v acc[4];
#pragma unroll
        for (int t = 0; t < 4; ++t) acc[t] = (f32x4v){0.f, 0.f, 0.f, 0.f};
        const __half* arow = inl + (w * 16 + col) * WSH + g * 8;
#pragma unroll
        for (int it = 0; it < 2; ++it) {
            half8v af = ld_frag(arow + it * 32);
            int J = it * 4 + g;
#pragma unroll
            for (int t = 0; t < 4; ++t) {
                int oo = 16 * t + col;
                half8v bf = ld_frag(W1t + oo * WSH + (((J ^ (oo >> 2)) & 7) << 3));
                acc[t] = __builtin_amdgcn_mfma_f32_16x16x32_f16(af, bf, acc[t], 0, 0, 0);
            }
        }
#pragma unroll
        for (int t = 0; t < 4; ++t)
#pragma unroll
            for (int r = 0; r < 4; ++r)
                t1l[(w * 16 + g * 4 + r) * WSH + 16 * t + col] = __float2half(silu_f(acc[t][r]));

        f32x4v acc2[2];
        acc2[0] = (f32x4v){0.f, 0.f, 0.f, 0.f};
        acc2[1] = (f32x4v){0.f, 0.f, 0.f, 0.f};
        const __half* arow2 = t1l + (w * 16 + col) * WSH + g * 8;
#pragma unroll
        for (int it = 0; it < 2; ++it) {
            half8v af = ld_frag(arow2 + it * 32);
            int J = it * 4 + g;
#pragma unroll
            for (int t = 0; t < 2; ++t) {
                int o2 = 16 * t + col;
                half8v bf = ld_frag(&W2t[c][o2 * WSH + (((J ^ (o2 >> 2)) & 7) << 3)]);
                acc2[t] = __builtin_amdgcn_mfma_f32_16x16x32_f16(af, bf, acc2[t], 0, 0, 0);
            }
        }
        float w3a = w3l[c * 32 + col], w3b = w3l[c * 32 + 16 + col];
#pragma unroll
        for (int r = 0; r < 4; ++r) {
            float p = silu_f(acc2[0][r]) * w3a + silu_f(acc2[1][r]) * w3b;
#pragma unroll
            for (int off = 1; off < 16; off <<= 1) p += __shfl_xor(p, off);
            yacc[r] += p;
        }
    }

    if (col == 0) {
#pragma unroll
        for (int r = 0; r < 4; ++r) ynode[w * 16 + g * 4 + r] = yacc[r];
    }
    __syncthreads();
    if (tid < 64) {
        int node = n0 + tid;
        bool act = node < N_ATOMS;
        float val = act ? ynode[tid] * 0.025f : 0.f;  // /sqrt(4)/20
        int b = act ? bat[min(node, N_ATOMS - 1)] : 0;
        unsigned long long rem = __ballot(act);
        while (rem) {
            int lead = (int)__ffsll(rem) - 1;
            int bl = __shfl(b, lead);
            bool mine = act && (b == bl);
            float t = mine ? val : 0.f;
#pragma unroll
            for (int off = 32; off; off >>= 1) t += __shfl_xor(t, off);
            if (tid == lead) atomicAdd(out + bl, t);
            rem &= ~__ballot(mine);
        }
    }
}

extern "C" void kernel_launch(void* const* d_in, const int* in_sizes, int n_in,
                              void* d_out, int out_size, void* d_ws, size_t ws_size,
                              hipStream_t stream) {
    const float* x     = (const float*)d_in[0];
    const int*   ei    = (const int*)d_in[1];
    const int*   bat   = (const int*)d_in[2];
    const float* gamma = (const float*)d_in[3];
    const float* beta  = (const float*)d_in[4];
    const float* Wc1   = (const float*)d_in[5];
    const float* as1   = (const float*)d_in[6];
    const float* ad1   = (const float*)d_in[7];
    const float* Wc2   = (const float*)d_in[8];
    const float* as2   = (const float*)d_in[9];
    const float* ad2   = (const float*)d_in[10];
    const float* Wn1   = (const float*)d_in[11];
    const float* Wn2   = (const float*)d_in[12];
    const float* Wout  = (const float*)d_in[13];
    float* out = (float*)d_out;

    // workspace layout (floats)
    float* A    = (float*)d_ws;            // C1h/C2h fp16 conv outs (channel-major)
    float* B    = A + 10240000;            // Bh fp16 proj h (channel-major)
    float* es   = B + 5120000;             // 80k (channel-major [c][N])
    float* ed   = es + 80000;              // 80k
    int* rowp   = (int*)(ed + 80000);      // 20001 (pad 20004)
    int* cnt    = rowp + 20004;            // 20000
    int* fillc  = cnt + 20000;             // 20000
    int* csr    = fillc + 20000;           // 400000
    int* bsum   = csr + 400000;            // 128
    int* boff   = bsum + 128;              // 128
    __half* C1h = (__half*)A;              // conv1 out (silu'd, fp16) [C][N][64]
    __half* C2h = (__half*)(A + 2560000);  // conv2 out (silu'd, fp16) [C][N][64]
    __half* Bh  = (__half*)B;              // proj h (fp16) [C][N][64]

    dim3 blk(256);
    const int NB = (N_ATOMS + 255) / 256;   // 79
    const int NT64 = (N_ATOMS + 63) / 64;   // 313

    // ---- CSR build (graph is shared by both convs) ----
    fill_kernel<<<80, blk, 0, stream>>>((float*)cnt, 40000, 0.f);  // cnt + fillc (adjacent)
    hist_kernel<<<(N_EDGES + 255) / 256, blk, 0, stream>>>(ei, cnt, N_EDGES);
    scan_l1_kernel<<<NB, blk, 0, stream>>>(cnt, rowp, bsum, N_ATOMS);
    scan_l2_kernel<<<1, blk, 0, stream>>>(bsum, boff, rowp + N_ATOMS, NB, out);
    scan_l3_kernel<<<NB, blk, 0, stream>>>(rowp, boff, N_ATOMS);
    scatter_kernel<<<(N_EDGES + 255) / 256, blk, 0, stream>>>(ei, rowp, fillc, csr, N_EDGES);

    // ---- conv1 (LN fused; h fp16 channel-major) ----
    proj_kernel<128, NCH * F_IN, false, false, true, true, false, true, true>
        <<<dim3(NT64, NCH), blk, 0, stream>>>(x, gamma, beta, Wc1, as1, ad1, Bh, es, ed);
    gat_gather_kernel<<<dim3(N_ATOMS / 16, NCH), blk, 0, stream>>>(rowp, csr, es, ed, Bh, C1h);

    // ---- conv2 (channel-major fp16 in/out) ----
    proj_kernel<64, 64, true, true, false, true, false, true, true>
        <<<dim3(NT64, NCH), blk, 0, stream>>>(C1h, gamma, beta, Wc2, as2, ad2, Bh, es, ed);
    gat_gather_kernel<<<dim3(N_ATOMS / 16, NCH), blk, 0, stream>>>(rowp, csr, es, ed, Bh, C2h);

    // ---- fused MLP head: two MFMA stages + energy reduction ----
    mlp_fused_kernel<<<NT64, blk, 0, stream>>>(C2h, Wn1, Wn2, Wout, bat, out);
}

// Round 23
// 172.848 us; speedup vs baseline: 1.1776x; 1.0043x over previous
//
#include <hip/hip_runtime.h>
#include <hip/hip_bf16.h>
#include <hip/hip_fp16.h>

// Problem constants (match reference)
#define N_ATOMS 20000
#define N_EDGES 400000
#define NCH 4
#define F_IN 128
#define S_OUT 32

// ---------- helpers ----------
__device__ __forceinline__ float silu_f(float v) { return v / (1.f + __expf(-v)); }

typedef _Float16 half8v __attribute__((ext_vector_type(8)));
typedef float f32x4v __attribute__((ext_vector_type(4)));

__device__ __forceinline__ half8v ld_frag(const __half* p) {
    union { float4 f; half8v h; } u;
    u.f = *(const float4*)p;
    return u.h;
}

__device__ __forceinline__ int wave_iscan(int v, int l) {
#pragma unroll
    for (int off = 1; off < 64; off <<= 1) {
        int t = __shfl_up(v, off);
        if (l >= off) v += t;
    }
    return v;
}

// ---------- fill ----------
__global__ void fill_kernel(float* __restrict__ p, int n, float v) {
    int i = blockIdx.x * blockDim.x + threadIdx.x;
    int stride = gridDim.x * blockDim.x;
    for (; i < n; i += stride) p[i] = v;
}

// ---------- CSR build: histogram -> 2-level scan (boff folded at use) -> scatter ----------
__global__ void hist_kernel(const int* __restrict__ ei, int* __restrict__ cnt, int E) {
    int e = blockIdx.x * 256 + threadIdx.x;
    if (e < E) atomicAdd(&cnt[ei[E + e]], 1);
}

__global__ __launch_bounds__(256) void scan_l1_kernel(const int* __restrict__ cnt,
                                                      int* __restrict__ rowp,
                                                      int* __restrict__ bsum, int n) {
    int i = blockIdx.x * 256 + threadIdx.x;
    int l = threadIdx.x & 63, w = threadIdx.x >> 6;
    int v = (i < n) ? cnt[i] : 0;
    int incl = wave_iscan(v, l);
    __shared__ int wsum[4];
    if (l == 63) wsum[w] = incl;
    __syncthreads();
    int add = 0;
#pragma unroll
    for (int j = 0; j < 4; ++j) add += (j < w) ? wsum[j] : 0;
    if (i < n) rowp[i] = add + incl - v;
    if (threadIdx.x == 255) bsum[blockIdx.x] = add + incl;
}

__global__ __launch_bounds__(256) void scan_l2_kernel(const int* __restrict__ bsum,
                                                      int* __restrict__ boff, int nb,
                                                      float* __restrict__ out_zero) {
    int i = threadIdx.x;
    if (i < S_OUT) out_zero[i] = 0.f;  // fused energies zero-init
    int l = i & 63, w = i >> 6;
    int v = (i < nb) ? bsum[i] : 0;
    int incl = wave_iscan(v, l);
    __shared__ int wsum[4];
    if (l == 63) wsum[w] = incl;
    __syncthreads();
    int add = 0;
#pragma unroll
    for (int j = 0; j < 4; ++j) add += (j < w) ? wsum[j] : 0;
    if (i < nb) boff[i] = add + incl - v;
}

__global__ void scatter_kernel(const int* __restrict__ ei, const int* __restrict__ rowp,
                               const int* __restrict__ boff,
                               int* __restrict__ fill, int* __restrict__ csr_src, int E) {
    int e = blockIdx.x * 256 + threadIdx.x;
    if (e < E) {
        int d = ei[E + e];
        int pos = rowp[d] + boff[d >> 8] + atomicAdd(&fill[d], 1);
        csr_src[pos] = ei[e];
    }
}

// ---------- projection via MFMA: block = 64 nodes x 64 outputs, c = blockIdx.y ----------
// IN_CMAJ/OUT_CMAJ: channel-major planes [c][node][64]. es/ed channel-major [c][node].
template <int FIN, int IN_STRIDE, bool IN_HALF, bool IN_CMAJ, bool LN, bool ATT,
          bool SILU_OUT, bool OUT_HALF, bool OUT_CMAJ>
__global__ __launch_bounds__(256) void proj_kernel(const void* __restrict__ inv,
                                                   const float* __restrict__ gamma,
                                                   const float* __restrict__ beta,
                                                   const float* __restrict__ W,
                                                   const float* __restrict__ a_src,
                                                   const float* __restrict__ a_dst,
                                                   void* __restrict__ outv,
                                                   float* __restrict__ es,
                                                   float* __restrict__ ed) {
    constexpr int OCT = FIN / 8;      // octets per row
    constexpr int OM = OCT - 1;
    constexpr int WSH = FIN + 8;      // halves stride (rows 16B-aligned)
    __shared__ __half Wt[64 * WSH];   // [o][store-swizzled k]
    __shared__ __half inl[64 * WSH];  // [node][k] linear
    const int tid = threadIdx.x;
    const int c = blockIdx.y;
    const int n0 = blockIdx.x * 64;
    const int w = tid >> 6;           // wave 0..3
    const int l = tid & 63;
    const int col = l & 15;           // MFMA row/col lane index
    const int g = l >> 4;             // k-octet group 0..3

    const float* __restrict__ Wc = W + c * (FIN * 64);
    for (int i = tid; i < (FIN / 2) * 64; i += 256) {
        int kp = i >> 6, oo = i & 63;
        int k = kp * 2;
        float w0 = Wc[(size_t)k * 64 + oo];
        float w1 = Wc[(size_t)(k + 1) * 64 + oo];
        int pos = ((((k >> 3) ^ (oo >> 2)) & OM) << 3) | (k & 7);
        *(__half2*)(&Wt[oo * WSH + pos]) = __floats2half2_rn(w0, w1);
    }
    if (IN_HALF) {
        const __half* __restrict__ inh = (const __half*)inv;
        for (int i = tid; i < 64 * (FIN / 8); i += 256) {
            int nl = i / (FIN / 8), ch = i % (FIN / 8);
            int node = min(n0 + nl, N_ATOMS - 1);
            const __half* src = IN_CMAJ
                ? inh + ((size_t)c * N_ATOMS + node) * 64 + ch * 8
                : inh + (size_t)node * IN_STRIDE + c * FIN + ch * 8;
            *(float4*)(inl + nl * WSH + ch * 8) = *(const float4*)src;
        }
    } else {
        const float* __restrict__ inf = (const float*)inv;
        for (int i = tid; i < 64 * (FIN / 8); i += 256) {
            int nl = i / (FIN / 8), ch = i % (FIN / 8);
            int node = min(n0 + nl, N_ATOMS - 1);
            const float* src = inf + (size_t)node * IN_STRIDE + c * FIN + ch * 8;
            float4 a = *(const float4*)src;
            float4 b = *(const float4*)(src + 4);
            float4 st;
            __half2* sp = (__half2*)&st;
            sp[0] = __floats2half2_rn(a.x, a.y);
            sp[1] = __floats2half2_rn(a.z, a.w);
            sp[2] = __floats2half2_rn(b.x, b.y);
            sp[3] = __floats2half2_rn(b.z, b.w);
            *(float4*)(inl + nl * WSH + ch * 8) = st;
        }
    }
    __syncthreads();

    if (LN) {  // parallel LayerNorm: 4 rows/wave concurrently, 16-lane-group reduce
        int sub = l >> 4;
        int l16 = l & 15;
        float gv[8], bv8[8];
#pragma unroll
        for (int j = 0; j < 8; ++j) {
            gv[j] = gamma[l16 * 8 + j];
            bv8[j] = beta[l16 * 8 + j];
        }
#pragma unroll
        for (int it = 0; it < 4; ++it) {
            int row = w * 16 + it * 4 + sub;
            __half* rp = inl + row * WSH + l16 * 8;
            float4 raw = *(const float4*)rp;
            __half2* hp = (__half2*)&raw;
            float v[8];
#pragma unroll
            for (int j = 0; j < 4; ++j) {
                float2 f = __half22float2(hp[j]);
                v[2 * j] = f.x;
                v[2 * j + 1] = f.y;
            }
            float s = 0.f, sq = 0.f;
#pragma unroll
            for (int j = 0; j < 8; ++j) { s += v[j]; sq += v[j] * v[j]; }
#pragma unroll
            for (int off = 1; off < 16; off <<= 1) {
                s += __shfl_xor(s, off);
                sq += __shfl_xor(sq, off);
            }
            float mu = s * (1.f / 128.f);
            float rs = rsqrtf(sq * (1.f / 128.f) - mu * mu + 1e-5f);
            float4 st;
            __half2* sp = (__half2*)&st;
#pragma unroll
            for (int j = 0; j < 4; ++j)
                sp[j] = __floats2half2_rn((v[2 * j] - mu) * rs * gv[2 * j] + bv8[2 * j],
                                          (v[2 * j + 1] - mu) * rs * gv[2 * j + 1] + bv8[2 * j + 1]);
            *(float4*)rp = st;
        }
        __syncthreads();
    }

    f32x4v acc[4];
#pragma unroll
    for (int t = 0; t < 4; ++t) acc[t] = (f32x4v){0.f, 0.f, 0.f, 0.f};

    const __half* arow = inl + (w * 16 + col) * WSH + g * 8;
#pragma unroll
    for (int it = 0; it < FIN / 32; ++it) {
        half8v af = ld_frag(arow + it * 32);
        int J = it * 4 + g;
#pragma unroll
        for (int t = 0; t < 4; ++t) {
            int oo = 16 * t + col;
            half8v bf = ld_frag(Wt + oo * WSH + (((J ^ (oo >> 2)) & OM) << 3));
            acc[t] = __builtin_amdgcn_mfma_f32_16x16x32_f16(af, bf, acc[t], 0, 0, 0);
        }
    }

    // epilogue: D layout col=lane&15, row=(lane>>4)*4+reg
    float av[4], bv[4];
    if (ATT) {
#pragma unroll
        for (int t = 0; t < 4; ++t) {
            av[t] = a_src[c * 64 + 16 * t + col];
            bv[t] = a_dst[c * 64 + 16 * t + col];
        }
    }
#pragma unroll
    for (int r = 0; r < 4; ++r) {
        int node = n0 + w * 16 + g * 4 + r;
        bool valid = node < N_ATOMS;
        if (valid) {
#pragma unroll
            for (int t = 0; t < 4; ++t) {
                float o = acc[t][r];
                if (SILU_OUT) o = silu_f(o);
                size_t idx = OUT_CMAJ ? ((size_t)c * N_ATOMS + node) * 64 + 16 * t + col
                                      : (size_t)node * 256 + c * 64 + 16 * t + col;
                if (OUT_HALF)
                    ((__half*)outv)[idx] = __float2half(o);
                else
                    ((float*)outv)[idx] = o;
            }
        }
        if (ATT) {
            float ps = 0.f, pd = 0.f;
#pragma unroll
            for (int t = 0; t < 4; ++t) {
                ps = fmaf(acc[t][r], av[t], ps);
                pd = fmaf(acc[t][r], bv[t], pd);
            }
#pragma unroll
            for (int off = 1; off < 16; off <<= 1) {
                ps += __shfl_xor(ps, off);
                pd += __shfl_xor(pd, off);
            }
            if (col == 0 && valid) {
                es[(size_t)c * N_ATOMS + node] = ps;   // channel-major
                ed[(size_t)c * N_ATOMS + node] = pd;
            }
        }
    }
}

// ---------- GAT aggregation: channel-phased, wave = 4 dsts x 1 channel ----------
// Phase B: 16B/lane loads -> one instruction serves TWO edges (8 lanes/row);
// lane sub=q>>3 takes edge parity, f8=q&7 the feature octet. shfl_xor(8) combine.
__global__ __launch_bounds__(256) void gat_gather_kernel(const int* __restrict__ rowp,
                                                         const int* __restrict__ boff,
                                                         const int* __restrict__ csr_src,
                                                         const float* __restrict__ es,
                                                         const float* __restrict__ ed,
                                                         const __half* __restrict__ h,
                                                         __half* __restrict__ out) {
    int l = threadIdx.x & 63;
    int wv = threadIdx.x >> 6;
    int c = blockIdx.y;
    int g = l >> 4, q = l & 15, grp = l & 48;
    int sub = q >> 3, f8 = q & 7;
    int d = blockIdx.x * 16 + wv * 4 + g;          // N divisible by 16
    const __half* __restrict__ hc = h + (size_t)c * N_ATOMS * 64;
    const float* __restrict__ esc = es + (size_t)c * N_ATOMS;
    int r0 = rowp[d] + boff[d >> 8];
    int r1 = (d == N_ATOMS - 1) ? N_EDGES : rowp[d + 1] + boff[(d + 1) >> 8];
    int deg = r1 - r0;
    float edc = ed[(size_t)c * N_ATOMS + d];
    int maxdeg = deg;
#pragma unroll
    for (int off = 16; off < 64; off <<= 1) maxdeg = max(maxdeg, __shfl_xor(maxdeg, off));

    float m = -1e30f, den = 0.f;
    float a[8];
#pragma unroll
    for (int j = 0; j < 8; ++j) a[j] = 0.f;

    for (int bo = 0; bo < maxdeg; bo += 16) {
        int len = min(16, deg - bo);               // may be <= 0 for finished groups
        // phase A: lanes q = edge slots within the group
        float logit = -1e30f;
        int s = 0;
        if (q < len) {
            s = csr_src[r0 + bo + q];
            float v = esc[s] + edc;
            logit = v >= 0.f ? v : 0.2f * v;
        }
        float cm = logit;
#pragma unroll
        for (int off = 8; off; off >>= 1) cm = fmaxf(cm, __shfl_xor(cm, off));
        float nm = fmaxf(m, cm);
        float resc = __expf(m - nm);
        float ex = (q < len) ? __expf(logit - nm) : 0.f;
        float cs = ex;
#pragma unroll
        for (int off = 8; off; off >>= 1) cs += __shfl_xor(cs, off);
        den = den * resc + cs;
#pragma unroll
        for (int j = 0; j < 8; ++j) a[j] *= resc;
        m = nm;
        // phase B: iteration j handles edges 2j (lanes sub=0) and 2j+1 (sub=1);
        // one 16B/lane load = 2 full rows per instruction. ex==0 beyond len.
#pragma unroll
        for (int j = 0; j < 8; ++j) {
            int e = 2 * j + sub;
            int se = __shfl(s, grp | e);
            float xe = __shfl(ex, grp | e);
            float4 hv = *(const float4*)(hc + (size_t)se * 64 + f8 * 8);
            __half2* hp = (__half2*)&hv;
#pragma unroll
            for (int t = 0; t < 4; ++t) {
                float2 f = __half22float2(hp[t]);
                a[2 * t] = fmaf(xe, f.x, a[2 * t]);
                a[2 * t + 1] = fmaf(xe, f.y, a[2 * t + 1]);
            }
        }
    }
    // combine edge-parity partials (lanes q and q^8 hold same features)
#pragma unroll
    for (int j = 0; j < 8; ++j) a[j] += __shfl_xor(a[j], 8);
    if (sub == 0) {
        float inv = 1.f / (den + 1e-16f);
        float4 st;
        __half2* sp = (__half2*)&st;
#pragma unroll
        for (int t = 0; t < 4; ++t)
            sp[t] = __floats2half2_rn(silu_f(a[2 * t] * inv), silu_f(a[2 * t + 1] * inv));
        *(float4*)(out + ((size_t)c * N_ATOMS + d) * 64 + f8 * 8) = st;
    }
}

// ---------- fused MLP head: two MFMA stages (64->64->32->1) + energy reduction ----------
__global__ __launch_bounds__(256) void mlp_fused_kernel(const __half* __restrict__ in,
                                                        const float* __restrict__ W1,
                                                        const float* __restrict__ W2,
                                                        const float* __restrict__ W3,
                                                        const int* __restrict__ bat,
                                                        float* __restrict__ out) {
    constexpr int WSH = 72;           // 64+8 halves
    __shared__ __half W1t[64 * WSH];  // [o][swz k] for current channel
    __shared__ __half inl[64 * WSH];  // [node][k]
    __shared__ __half t1l[64 * WSH];  // [node][o] (linear)
    __shared__ __half W2t[NCH][32 * WSH];  // all channels, staged once
    __shared__ float w3l[NCH * 32];
    __shared__ float ynode[64];
    const int tid = threadIdx.x;
    const int n0 = blockIdx.x * 64;
    const int w = tid >> 6;
    const int l = tid & 63;
    const int col = l & 15;
    const int g = l >> 4;

    for (int i = tid; i < NCH * 32 * 32; i += 256) {
        int cc = i >> 10, rem = i & 1023;
        int kp = rem >> 5, o2 = rem & 31;
        int k = kp * 2;
        float a = W2[cc * 2048 + k * 32 + o2];
        float b = W2[cc * 2048 + (k + 1) * 32 + o2];
        int pos = ((((k >> 3) ^ (o2 >> 2)) & 7) << 3) | (k & 7);
        *(__half2*)(&W2t[cc][o2 * WSH + pos]) = __floats2half2_rn(a, b);
    }
    if (tid < NCH * 32) w3l[tid] = W3[tid];

    float yacc[4] = {0.f, 0.f, 0.f, 0.f};

    for (int c = 0; c < NCH; ++c) {
        __syncthreads();
        for (int i = tid; i < 32 * 64; i += 256) {
            int kp = i >> 6, oo = i & 63;
            int k = kp * 2;
            float a = W1[c * 4096 + k * 64 + oo];
            float b = W1[c * 4096 + (k + 1) * 64 + oo];
            int pos = ((((k >> 3) ^ (oo >> 2)) & 7) << 3) | (k & 7);
            *(__half2*)(&W1t[oo * WSH + pos]) = __floats2half2_rn(a, b);
        }
        for (int i = tid; i < 64 * 8; i += 256) {
            int nl = i >> 3, ch = i & 7;
            int node = min(n0 + nl, N_ATOMS - 1);
            *(float4*)(inl + nl * WSH + ch * 8) =
                *(const float4*)(in + ((size_t)c * N_ATOMS + node) * 64 + ch * 8);
        }
        __syncthreads();

        f32x4v acc[4];
#pragma unroll
        for (int t = 0; t < 4; ++t) acc[t] = (f32x4v){0.f, 0.f, 0.f, 0.f};
        const __half* arow = inl + (w * 16 + col) * WSH + g * 8;
#pragma unroll
        for (int it = 0; it < 2; ++it) {
            half8v af = ld_frag(arow + it * 32);
            int J = it * 4 + g;
#pragma unroll
            for (int t = 0; t < 4; ++t) {
                int oo = 16 * t + col;
                half8v bf = ld_frag(W1t + oo * WSH + (((J ^ (oo >> 2)) & 7) << 3));
                acc[t] = __builtin_amdgcn_mfma_f32_16x16x32_f16(af, bf, acc[t], 0, 0, 0);
            }
        }
#pragma unroll
        for (int t = 0; t < 4; ++t)
#pragma unroll
            for (int r = 0; r < 4; ++r)
                t1l[(w * 16 + g * 4 + r) * WSH + 16 * t + col] = __float2half(silu_f(acc[t][r]));

        f32x4v acc2[2];
        acc2[0] = (f32x4v){0.f, 0.f, 0.f, 0.f};
        acc2[1] = (f32x4v){0.f, 0.f, 0.f, 0.f};
        const __half* arow2 = t1l + (w * 16 + col) * WSH + g * 8;
#pragma unroll
        for (int it = 0; it < 2; ++it) {
            half8v af = ld_frag(arow2 + it * 32);
            int J = it * 4 + g;
#pragma unroll
            for (int t = 0; t < 2; ++t) {
                int o2 = 16 * t + col;
                half8v bf = ld_frag(&W2t[c][o2 * WSH + (((J ^ (o2 >> 2)) & 7) << 3)]);
                acc2[t] = __builtin_amdgcn_mfma_f32_16x16x32_f16(af, bf, acc2[t], 0, 0, 0);
            }
        }
        float w3a = w3l[c * 32 + col], w3b = w3l[c * 32 + 16 + col];
#pragma unroll
        for (int r = 0; r < 4; ++r) {
            float p = silu_f(acc2[0][r]) * w3a + silu_f(acc2[1][r]) * w3b;
#pragma unroll
            for (int off = 1; off < 16; off <<= 1) p += __shfl_xor(p, off);
            yacc[r] += p;
        }
    }

    if (col == 0) {
#pragma unroll
        for (int r = 0; r < 4; ++r) ynode[w * 16 + g * 4 + r] = yacc[r];
    }
    __syncthreads();
    if (tid < 64) {
        int node = n0 + tid;
        bool act = node < N_ATOMS;
        float val = act ? ynode[tid] * 0.025f : 0.f;  // /sqrt(4)/20
        int b = act ? bat[min(node, N_ATOMS - 1)] : 0;
        unsigned long long rem = __ballot(act);
        while (rem) {
            int lead = (int)__ffsll(rem) - 1;
            int bl = __shfl(b, lead);
            bool mine = act && (b == bl);
            float t = mine ? val : 0.f;
#pragma unroll
            for (int off = 32; off; off >>= 1) t += __shfl_xor(t, off);
            if (tid == lead) atomicAdd(out + bl, t);
            rem &= ~__ballot(mine);
        }
    }
}

extern "C" void kernel_launch(void* const* d_in, const int* in_sizes, int n_in,
                              void* d_out, int out_size, void* d_ws, size_t ws_size,
                              hipStream_t stream) {
    const float* x     = (const float*)d_in[0];
    const int*   ei    = (const int*)d_in[1];
    const int*   bat   = (const int*)d_in[2];
    const float* gamma = (const float*)d_in[3];
    const float* beta  = (const float*)d_in[4];
    const float* Wc1   = (const float*)d_in[5];
    const float* as1   = (const float*)d_in[6];
    const float* ad1   = (const float*)d_in[7];
    const float* Wc2   = (const float*)d_in[8];
    const float* as2   = (const float*)d_in[9];
    const float* ad2   = (const float*)d_in[10];
    const float* Wn1   = (const float*)d_in[11];
    const float* Wn2   = (const float*)d_in[12];
    const float* Wout  = (const float*)d_in[13];
    float* out = (float*)d_out;

    // workspace layout (floats)
    float* A    = (float*)d_ws;            // C1h/C2h fp16 conv outs (channel-major)
    float* B    = A + 10240000;            // Bh fp16 proj h (channel-major)
    float* es   = B + 5120000;             // 80k (channel-major [c][N])
    float* ed   = es + 80000;              // 80k
    int* rowp   = (int*)(ed + 80000);      // 20001 (pad 20004)
    int* cnt    = rowp + 20004;            // 20000
    int* fillc  = cnt + 20000;             // 20000
    int* csr    = fillc + 20000;           // 400000
    int* bsum   = csr + 400000;            // 128
    int* boff   = bsum + 128;              // 128
    __half* C1h = (__half*)A;              // conv1 out (silu'd, fp16) [C][N][64]
    __half* C2h = (__half*)(A + 2560000);  // conv2 out (silu'd, fp16) [C][N][64]
    __half* Bh  = (__half*)B;              // proj h (fp16) [C][N][64]

    dim3 blk(256);
    const int NB = (N_ATOMS + 255) / 256;   // 79
    const int NT64 = (N_ATOMS + 63) / 64;   // 313

    // ---- CSR build (graph is shared by both convs) ----
    fill_kernel<<<80, blk, 0, stream>>>((float*)cnt, 40000, 0.f);  // cnt + fillc (adjacent)
    hist_kernel<<<(N_EDGES + 255) / 256, blk, 0, stream>>>(ei, cnt, N_EDGES);
    scan_l1_kernel<<<NB, blk, 0, stream>>>(cnt, rowp, bsum, N_ATOMS);
    scan_l2_kernel<<<1, blk, 0, stream>>>(bsum, boff, NB, out);
    scatter_kernel<<<(N_EDGES + 255) / 256, blk, 0, stream>>>(ei, rowp, boff, fillc, csr, N_EDGES);

    // ---- conv1 (LN fused; h fp16 channel-major) ----
    proj_kernel<128, NCH * F_IN, false, false, true, true, false, true, true>
        <<<dim3(NT64, NCH), blk, 0, stream>>>(x, gamma, beta, Wc1, as1, ad1, Bh, es, ed);
    gat_gather_kernel<<<dim3(N_ATOMS / 16, NCH), blk, 0, stream>>>(rowp, boff, csr, es, ed, Bh, C1h);

    // ---- conv2 (channel-major fp16 in/out) ----
    proj_kernel<64, 64, true, true, false, true, false, true, true>
        <<<dim3(NT64, NCH), blk, 0, stream>>>(C1h, gamma, beta, Wc2, as2, ad2, Bh, es, ed);
    gat_gather_kernel<<<dim3(N_ATOMS / 16, NCH), blk, 0, stream>>>(rowp, boff, csr, es, ed, Bh, C2h);

    // ---- fused MLP head: two MFMA stages + energy reduction ----
    mlp_fused_kernel<<<NT64, blk, 0, stream>>>(C2h, Wn1, Wn2, Wout, bat, out);
}